// Round 1
// baseline (2437.284 us; speedup 1.0000x reference)
//
#include <hip/hip_runtime.h>
#include <hip/hip_bf16.h>
#include <stdint.h>

#define NB 8
#define NS 256
#define NH 512
#define NG 1024
#define NV 256
#define NL 24
#define NC 320
#define NT 2048
#define EPSF 1e-5f

typedef __bf16 bf16;
typedef bf16 bf16x8 __attribute__((ext_vector_type(8)));
typedef float f32x4 __attribute__((ext_vector_type(4)));

__device__ __forceinline__ bf16 f2bf(float f) {
    uint32_t u = __builtin_bit_cast(uint32_t, f);
    u += 0x7FFFu + ((u >> 16) & 1u);
    uint16_t b = (uint16_t)(u >> 16);
    return __builtin_bit_cast(bf16, b);
}

// ---------------- stem: h[t,o] = sum_c stem_w[o,c] * x[b,c,s];  + ss for rl[0]
__global__ __launch_bounds__(256) void k_stem(
    const float* __restrict__ x, const float* __restrict__ w,
    float* __restrict__ h, float* __restrict__ ss_out)
{
    __shared__ bf16 As[64*40];
    __shared__ bf16 Bs[64*40];
    __shared__ float Cs[64*66];
    const int t0 = blockIdx.x*64, n0 = blockIdx.y*64;
    const int b = t0 >> 8, s0 = t0 & 255;
    const int tid = threadIdx.x, lane = tid & 63, wv_ = tid >> 6;
    const int wm = wv_ >> 1, wn = wv_ & 1;
    const int rr = tid >> 2, cc8 = (tid & 3)*8;
    f32x4 acc[2][2] = {};
    for (int k0 = 0; k0 < NC; k0 += 32) {
        #pragma unroll
        for (int e = 0; e < 8; ++e) {
            int idx = tid + e*256;
            int c = idx >> 6, r = idx & 63;
            As[r*40 + c] = f2bf(x[(size_t)(b*NC + k0 + c)*NS + s0 + r]);
        }
        {
            const float* src = &w[(size_t)(n0 + rr)*NC + k0 + cc8];
            bf16x8 t;
            #pragma unroll
            for (int i = 0; i < 8; ++i) t[i] = f2bf(src[i]);
            *(bf16x8*)&Bs[rr*40 + cc8] = t;
        }
        __syncthreads();
        const int fr = lane & 15, kg = (lane >> 4)*8;
        bf16x8 a0 = *(const bf16x8*)&As[(wm*32 + fr)*40 + kg];
        bf16x8 a1 = *(const bf16x8*)&As[(wm*32 + 16 + fr)*40 + kg];
        bf16x8 b0 = *(const bf16x8*)&Bs[(wn*32 + fr)*40 + kg];
        bf16x8 b1 = *(const bf16x8*)&Bs[(wn*32 + 16 + fr)*40 + kg];
        acc[0][0] = __builtin_amdgcn_mfma_f32_16x16x32_bf16(a0, b0, acc[0][0], 0,0,0);
        acc[0][1] = __builtin_amdgcn_mfma_f32_16x16x32_bf16(a0, b1, acc[0][1], 0,0,0);
        acc[1][0] = __builtin_amdgcn_mfma_f32_16x16x32_bf16(a1, b0, acc[1][0], 0,0,0);
        acc[1][1] = __builtin_amdgcn_mfma_f32_16x16x32_bf16(a1, b1, acc[1][1], 0,0,0);
        __syncthreads();
    }
    const int row4 = (lane >> 4)*4, col = lane & 15;
    #pragma unroll
    for (int mi = 0; mi < 2; ++mi)
      #pragma unroll
      for (int ni = 0; ni < 2; ++ni)
        #pragma unroll
        for (int r = 0; r < 4; ++r)
            Cs[(wm*32 + mi*16 + row4 + r)*66 + wn*32 + ni*16 + col] = acc[mi][ni][r];
    __syncthreads();
    const int c16 = (tid & 3)*16;
    float ssum = 0.f;
    float* dst = &h[(size_t)(t0 + rr)*NH + n0 + c16];
    #pragma unroll
    for (int i = 0; i < 16; ++i) {
        float v = Cs[rr*66 + c16 + i];
        dst[i] = v;
        ssum += v*v;
    }
    ssum += __shfl_xor(ssum, 1, 64);
    ssum += __shfl_xor(ssum, 2, 64);
    if ((tid & 3) == 0) atomicAdd(&ss_out[t0 + rr], ssum);
}

// ---------------- local mix: per-channel 16x16 over within-chunk position j
__global__ __launch_bounds__(256) void k_local(
    float* __restrict__ h, const float* __restrict__ ss_in,
    const float* __restrict__ wl, const float* __restrict__ rmsw,
    const float* __restrict__ alpha_p, float* __restrict__ ss_out)
{
    __shared__ bf16 Wt[256*68];   // [p*16+j][c], c<64
    __shared__ float raw[16*64];
    __shared__ float rstdL[256];
    const int b = blockIdx.x, c0 = blockIdx.y*64;
    const int tid = threadIdx.x, lane = tid & 63, wv_ = tid >> 6;
    rstdL[tid] = rsqrtf(ss_in[b*NS + tid]*(1.f/NH) + EPSF);
    for (int e = 0; e < 64; ++e) {
        int idx = tid + e*256;
        int c = idx >> 8, pj = idx & 255;
        Wt[pj*68 + c] = f2bf(wl[(size_t)(c0 + c)*256 + pj]);
    }
    const float al = *alpha_p;
    const float rlc = rmsw[c0 + lane];
    __syncthreads();
    for (int i = 0; i < 16; ++i) {
        #pragma unroll
        for (int e = 0; e < 4; ++e) {
            int idx = tid + e*256;
            int j = idx >> 6, c = idx & 63;
            raw[j*64 + c] = h[(size_t)(b*NS + i*16 + j)*NH + c0 + c];
        }
        __syncthreads();
        #pragma unroll
        for (int pp = 0; pp < 4; ++pp) {
            int p = wv_*4 + pp;
            float acc = 0.f;
            #pragma unroll
            for (int j = 0; j < 16; ++j)
                acc += (float)Wt[(p*16 + j)*68 + lane] * raw[j*64 + lane] * rstdL[i*16 + j];
            float hn = raw[p*64 + lane] + al * rlc * acc;
            h[(size_t)(b*NS + i*16 + p)*NH + c0 + lane] = hn;
            float ssum = hn*hn;
            ssum += __shfl_xor(ssum, 1, 64);
            ssum += __shfl_xor(ssum, 2, 64);
            ssum += __shfl_xor(ssum, 4, 64);
            ssum += __shfl_xor(ssum, 8, 64);
            ssum += __shfl_xor(ssum, 16, 64);
            ssum += __shfl_xor(ssum, 32, 64);
            if (lane == 0) atomicAdd(&ss_out[b*NS + i*16 + p], ssum);
        }
        __syncthreads();
    }
}

// ---------------- global mix: per-channel 16x16 over chunk index i
__global__ __launch_bounds__(256) void k_global(
    float* __restrict__ h, const float* __restrict__ ss_in,
    const float* __restrict__ wgm, const float* __restrict__ rmsw,
    const float* __restrict__ alpha_p, float* __restrict__ ss_out)
{
    __shared__ bf16 Wt[256*40];   // [p*16+i][c], c<32
    __shared__ float raw[256*32];
    __shared__ float rstdL[256];
    const int b = blockIdx.x, c0 = blockIdx.y*32;
    const int tid = threadIdx.x;
    const int c = tid & 31, pg = tid >> 5;
    rstdL[tid] = rsqrtf(ss_in[b*NS + tid]*(1.f/NH) + EPSF);
    #pragma unroll
    for (int e = 0; e < 32; ++e) {
        int idx = tid + e*256;
        int cw = idx >> 8, pi = idx & 255;
        Wt[pi*40 + cw] = f2bf(wgm[(size_t)(c0 + cw)*256 + pi]);
    }
    #pragma unroll
    for (int e = 0; e < 32; ++e) {
        int idx = tid + e*256;
        int s = idx >> 5, cw = idx & 31;
        raw[s*32 + cw] = h[(size_t)(b*NS + s)*NH + c0 + cw];
    }
    const float ag = *alpha_p;
    const float rgc = rmsw[c0 + c];
    __syncthreads();
    for (int j = 0; j < 16; ++j) {
        #pragma unroll
        for (int pp = 0; pp < 2; ++pp) {
            int p = pg*2 + pp;
            float acc = 0.f;
            #pragma unroll
            for (int i = 0; i < 16; ++i)
                acc += (float)Wt[(p*16 + i)*40 + c] * raw[(i*16 + j)*32 + c] * rstdL[i*16 + j];
            float hn = raw[(p*16 + j)*32 + c] + ag * rgc * acc;
            h[(size_t)(b*NS + p*16 + j)*NH + c0 + c] = hn;
            float ssum = hn*hn;
            ssum += __shfl_xor(ssum, 1, 64);
            ssum += __shfl_xor(ssum, 2, 64);
            ssum += __shfl_xor(ssum, 4, 64);
            ssum += __shfl_xor(ssum, 8, 64);
            ssum += __shfl_xor(ssum, 16, 64);
            if (c == 0) atomicAdd(&ss_out[b*NS + p*16 + j], ssum);
        }
    }
}

// ---------------- mlp in: g = silu(wv . norm(h)) * (wg . norm(h))   (bf16 out)
__global__ __launch_bounds__(256) void k_mlp_in(
    const float* __restrict__ h, const float* __restrict__ ss_in,
    const float* __restrict__ rmsw, const float* __restrict__ wvl,
    const float* __restrict__ wgl, bf16* __restrict__ g)
{
    __shared__ bf16 As[64*40], Bs1[64*40], Bs3[64*40];
    __shared__ float rstdA[64], rw[NH];
    __shared__ bf16 Gs[64*72];
    const int t0 = blockIdx.x*64, n0 = blockIdx.y*64;
    const int tid = threadIdx.x, lane = tid & 63, wv_ = tid >> 6;
    const int wm = wv_ >> 1, wn = wv_ & 1;
    const int rr = tid >> 2, cc8 = (tid & 3)*8;
    if (tid < 64) rstdA[tid] = rsqrtf(ss_in[t0 + tid]*(1.f/NH) + EPSF);
    rw[tid] = rmsw[tid]; rw[tid + 256] = rmsw[tid + 256];
    __syncthreads();
    f32x4 acc1[2][2] = {}, acc3[2][2] = {};
    for (int k0 = 0; k0 < NH; k0 += 32) {
        {
            const float* src = &h[(size_t)(t0 + rr)*NH + k0 + cc8];
            float sc = rstdA[rr];
            bf16x8 t;
            #pragma unroll
            for (int i = 0; i < 8; ++i) t[i] = f2bf(src[i]*sc*rw[k0 + cc8 + i]);
            *(bf16x8*)&As[rr*40 + cc8] = t;
        }
        {
            const float* s1 = &wvl[(size_t)(n0 + rr)*NH + k0 + cc8];
            const float* s3 = &wgl[(size_t)(n0 + rr)*NH + k0 + cc8];
            bf16x8 t1, t3;
            #pragma unroll
            for (int i = 0; i < 8; ++i) { t1[i] = f2bf(s1[i]); t3[i] = f2bf(s3[i]); }
            *(bf16x8*)&Bs1[rr*40 + cc8] = t1;
            *(bf16x8*)&Bs3[rr*40 + cc8] = t3;
        }
        __syncthreads();
        const int fr = lane & 15, kg = (lane >> 4)*8;
        bf16x8 a0 = *(const bf16x8*)&As[(wm*32 + fr)*40 + kg];
        bf16x8 a1 = *(const bf16x8*)&As[(wm*32 + 16 + fr)*40 + kg];
        bf16x8 u0 = *(const bf16x8*)&Bs1[(wn*32 + fr)*40 + kg];
        bf16x8 u1 = *(const bf16x8*)&Bs1[(wn*32 + 16 + fr)*40 + kg];
        bf16x8 v0 = *(const bf16x8*)&Bs3[(wn*32 + fr)*40 + kg];
        bf16x8 v1 = *(const bf16x8*)&Bs3[(wn*32 + 16 + fr)*40 + kg];
        acc1[0][0] = __builtin_amdgcn_mfma_f32_16x16x32_bf16(a0, u0, acc1[0][0], 0,0,0);
        acc1[0][1] = __builtin_amdgcn_mfma_f32_16x16x32_bf16(a0, u1, acc1[0][1], 0,0,0);
        acc1[1][0] = __builtin_amdgcn_mfma_f32_16x16x32_bf16(a1, u0, acc1[1][0], 0,0,0);
        acc1[1][1] = __builtin_amdgcn_mfma_f32_16x16x32_bf16(a1, u1, acc1[1][1], 0,0,0);
        acc3[0][0] = __builtin_amdgcn_mfma_f32_16x16x32_bf16(a0, v0, acc3[0][0], 0,0,0);
        acc3[0][1] = __builtin_amdgcn_mfma_f32_16x16x32_bf16(a0, v1, acc3[0][1], 0,0,0);
        acc3[1][0] = __builtin_amdgcn_mfma_f32_16x16x32_bf16(a1, v0, acc3[1][0], 0,0,0);
        acc3[1][1] = __builtin_amdgcn_mfma_f32_16x16x32_bf16(a1, v1, acc3[1][1], 0,0,0);
        __syncthreads();
    }
    const int row4 = (lane >> 4)*4, col = lane & 15;
    #pragma unroll
    for (int mi = 0; mi < 2; ++mi)
      #pragma unroll
      for (int ni = 0; ni < 2; ++ni)
        #pragma unroll
        for (int r = 0; r < 4; ++r) {
            float xv = acc1[mi][ni][r];
            float gl = (xv / (1.f + __expf(-xv))) * acc3[mi][ni][r];
            Gs[(wm*32 + mi*16 + row4 + r)*72 + wn*32 + ni*16 + col] = f2bf(gl);
        }
    __syncthreads();
    const int c16 = (tid & 3)*16;
    bf16x8 o0 = *(const bf16x8*)&Gs[rr*72 + c16];
    bf16x8 o1 = *(const bf16x8*)&Gs[rr*72 + c16 + 8];
    *(bf16x8*)&g[(size_t)(t0 + rr)*NG + n0 + c16] = o0;
    *(bf16x8*)&g[(size_t)(t0 + rr)*NG + n0 + c16 + 8] = o1;
}

// ---------------- mlp out: h += alpha * (wo . g); + ss for next norm
__global__ __launch_bounds__(256) void k_mlp_out(
    const bf16* __restrict__ g, const float* __restrict__ wol,
    const float* __restrict__ alpha_p, float* __restrict__ h,
    float* __restrict__ ss_out)
{
    __shared__ bf16 As[64*40], Bs[64*40];
    __shared__ float Cs[64*66];
    const int t0 = blockIdx.x*64, n0 = blockIdx.y*64;
    const int tid = threadIdx.x, lane = tid & 63, wv_ = tid >> 6;
    const int wm = wv_ >> 1, wn = wv_ & 1;
    const int rr = tid >> 2, cc8 = (tid & 3)*8;
    f32x4 acc[2][2] = {};
    for (int k0 = 0; k0 < NG; k0 += 32) {
        *(bf16x8*)&As[rr*40 + cc8] = *(const bf16x8*)&g[(size_t)(t0 + rr)*NG + k0 + cc8];
        {
            const float* src = &wol[(size_t)(n0 + rr)*NG + k0 + cc8];
            bf16x8 t;
            #pragma unroll
            for (int i = 0; i < 8; ++i) t[i] = f2bf(src[i]);
            *(bf16x8*)&Bs[rr*40 + cc8] = t;
        }
        __syncthreads();
        const int fr = lane & 15, kg = (lane >> 4)*8;
        bf16x8 a0 = *(const bf16x8*)&As[(wm*32 + fr)*40 + kg];
        bf16x8 a1 = *(const bf16x8*)&As[(wm*32 + 16 + fr)*40 + kg];
        bf16x8 b0 = *(const bf16x8*)&Bs[(wn*32 + fr)*40 + kg];
        bf16x8 b1 = *(const bf16x8*)&Bs[(wn*32 + 16 + fr)*40 + kg];
        acc[0][0] = __builtin_amdgcn_mfma_f32_16x16x32_bf16(a0, b0, acc[0][0], 0,0,0);
        acc[0][1] = __builtin_amdgcn_mfma_f32_16x16x32_bf16(a0, b1, acc[0][1], 0,0,0);
        acc[1][0] = __builtin_amdgcn_mfma_f32_16x16x32_bf16(a1, b0, acc[1][0], 0,0,0);
        acc[1][1] = __builtin_amdgcn_mfma_f32_16x16x32_bf16(a1, b1, acc[1][1], 0,0,0);
        __syncthreads();
    }
    const int row4 = (lane >> 4)*4, col = lane & 15;
    #pragma unroll
    for (int mi = 0; mi < 2; ++mi)
      #pragma unroll
      for (int ni = 0; ni < 2; ++ni)
        #pragma unroll
        for (int r = 0; r < 4; ++r)
            Cs[(wm*32 + mi*16 + row4 + r)*66 + wn*32 + ni*16 + col] = acc[mi][ni][r];
    __syncthreads();
    const float am = *alpha_p;
    const int c16 = (tid & 3)*16;
    float* dst = &h[(size_t)(t0 + rr)*NH + n0 + c16];
    float ssum = 0.f;
    #pragma unroll
    for (int i = 0; i < 16; ++i) {
        float hn = dst[i] + am * Cs[rr*66 + c16 + i];
        dst[i] = hn;
        ssum += hn*hn;
    }
    ssum += __shfl_xor(ssum, 1, 64);
    ssum += __shfl_xor(ssum, 2, 64);
    if ((tid & 3) == 0) atomicAdd(&ss_out[t0 + rr], ssum);
}

// ---------------- head: logits[b,v,s] = scale * head_w . (norm(h)*head_rms)
__global__ __launch_bounds__(256) void k_head(
    const float* __restrict__ h, const float* __restrict__ ss_in,
    const float* __restrict__ rmsw, const float* __restrict__ hw,
    const float* __restrict__ scale_p, float* __restrict__ out)
{
    __shared__ bf16 As[64*40], Bs[64*40];
    __shared__ float Ls[64*66];
    __shared__ float rstdA[64], rw[NH];
    const int t0 = blockIdx.x*64, n0 = blockIdx.y*64;
    const int tid = threadIdx.x, lane = tid & 63, wv_ = tid >> 6;
    const int wm = wv_ >> 1, wn = wv_ & 1;
    const int rr = tid >> 2, cc8 = (tid & 3)*8;
    if (tid < 64) rstdA[tid] = rsqrtf(ss_in[t0 + tid]*(1.f/NH) + EPSF);
    rw[tid] = rmsw[tid]; rw[tid + 256] = rmsw[tid + 256];
    __syncthreads();
    f32x4 acc[2][2] = {};
    for (int k0 = 0; k0 < NH; k0 += 32) {
        {
            const float* src = &h[(size_t)(t0 + rr)*NH + k0 + cc8];
            float sc = rstdA[rr];
            bf16x8 t;
            #pragma unroll
            for (int i = 0; i < 8; ++i) t[i] = f2bf(src[i]*sc*rw[k0 + cc8 + i]);
            *(bf16x8*)&As[rr*40 + cc8] = t;
        }
        {
            const float* src = &hw[(size_t)(n0 + rr)*NH + k0 + cc8];
            bf16x8 t;
            #pragma unroll
            for (int i = 0; i < 8; ++i) t[i] = f2bf(src[i]);
            *(bf16x8*)&Bs[rr*40 + cc8] = t;
        }
        __syncthreads();
        const int fr = lane & 15, kg = (lane >> 4)*8;
        bf16x8 a0 = *(const bf16x8*)&As[(wm*32 + fr)*40 + kg];
        bf16x8 a1 = *(const bf16x8*)&As[(wm*32 + 16 + fr)*40 + kg];
        bf16x8 b0 = *(const bf16x8*)&Bs[(wn*32 + fr)*40 + kg];
        bf16x8 b1 = *(const bf16x8*)&Bs[(wn*32 + 16 + fr)*40 + kg];
        acc[0][0] = __builtin_amdgcn_mfma_f32_16x16x32_bf16(a0, b0, acc[0][0], 0,0,0);
        acc[0][1] = __builtin_amdgcn_mfma_f32_16x16x32_bf16(a0, b1, acc[0][1], 0,0,0);
        acc[1][0] = __builtin_amdgcn_mfma_f32_16x16x32_bf16(a1, b0, acc[1][0], 0,0,0);
        acc[1][1] = __builtin_amdgcn_mfma_f32_16x16x32_bf16(a1, b1, acc[1][1], 0,0,0);
        __syncthreads();
    }
    const float sc = *scale_p;
    const int row4 = (lane >> 4)*4, col = lane & 15;
    #pragma unroll
    for (int mi = 0; mi < 2; ++mi)
      #pragma unroll
      for (int ni = 0; ni < 2; ++ni)
        #pragma unroll
        for (int r = 0; r < 4; ++r)
            Ls[(wm*32 + mi*16 + row4 + r)*66 + wn*32 + ni*16 + col] = sc * acc[mi][ni][r];
    __syncthreads();
    const int vv = tid >> 2, s16 = (tid & 3)*16;
    const int b = t0 >> 8, s0 = t0 & 255;
    float* dst = &out[((size_t)(b*NV + n0 + vv))*NS + s0 + s16];
    #pragma unroll
    for (int i = 0; i < 16; ++i) dst[i] = Ls[(s16 + i)*66 + vv];
}

extern "C" void kernel_launch(void* const* d_in, const int* in_sizes, int n_in,
                              void* d_out, int out_size, void* d_ws, size_t ws_size,
                              hipStream_t stream) {
    const float* x          = (const float*)d_in[0];
    const float* stem_w     = (const float*)d_in[1];
    const float* rms_local  = (const float*)d_in[2];
    const float* rms_global = (const float*)d_in[3];
    const float* rms_ffn    = (const float*)d_in[4];
    const float* alpha_local  = (const float*)d_in[5];
    const float* alpha_global = (const float*)d_in[6];
    const float* alpha_mlp    = (const float*)d_in[7];
    const float* w_local    = (const float*)d_in[8];
    const float* w_global   = (const float*)d_in[9];
    const float* wv         = (const float*)d_in[10];
    const float* wg         = (const float*)d_in[11];
    const float* wo         = (const float*)d_in[12];
    const float* head_rms   = (const float*)d_in[13];
    const float* head_scale = (const float*)d_in[14];
    const float* head_w     = (const float*)d_in[15];
    float* out = (float*)d_out;

    char* ws = (char*)d_ws;
    float* h  = (float*)ws;                                   // 4 MB
    bf16*  g  = (bf16*)(ws + (size_t)4*1024*1024);            // 4 MB
    float* ss = (float*)(ws + (size_t)8*1024*1024);           // 73 * 2048 * 4
    float* ss_rl = ss;
    float* ss_rg = ss + 24*NT;
    float* ss_rf = ss + 48*NT;
    float* ss_hd = ss + 72*NT;

    hipMemsetAsync(ss, 0, (size_t)73*NT*sizeof(float), stream);

    k_stem<<<dim3(32, 8), 256, 0, stream>>>(x, stem_w, h, ss_rl);
    for (int l = 0; l < NL; ++l) {
        k_local<<<dim3(NB, 8), 256, 0, stream>>>(
            h, ss_rl + l*NT, w_local + (size_t)l*NH*256,
            rms_local + l*NH, alpha_local + l, ss_rg + l*NT);
        k_global<<<dim3(NB, 16), 256, 0, stream>>>(
            h, ss_rg + l*NT, w_global + (size_t)l*NH*256,
            rms_global + l*NH, alpha_global + l, ss_rf + l*NT);
        k_mlp_in<<<dim3(32, 16), 256, 0, stream>>>(
            h, ss_rf + l*NT, rms_ffn + l*NH,
            wv + (size_t)l*NG*NH, wg + (size_t)l*NG*NH, g);
        float* ssn = (l == NL-1) ? ss_hd : (ss_rl + (l+1)*NT);
        k_mlp_out<<<dim3(32, 8), 256, 0, stream>>>(
            g, wo + (size_t)l*NH*NG, alpha_mlp + l, h, ssn);
    }
    k_head<<<dim3(32, 4), 256, 0, stream>>>(h, ss_hd, head_rms, head_w, head_scale, out);
}

// Round 3
// 1771.757 us; speedup vs baseline: 1.3756x; 1.3756x over previous
//
#include <hip/hip_runtime.h>
#include <hip/hip_bf16.h>
#include <stdint.h>

#define NB 8
#define NS 256
#define NH 512
#define NG 1024
#define NV 256
#define NL 24
#define NC 320
#define NT 2048
#define EPSF 1e-5f

typedef __bf16 bf16;
typedef bf16 bf16x8 __attribute__((ext_vector_type(8)));
typedef float f32x4 __attribute__((ext_vector_type(4)));

__device__ __forceinline__ bf16 f2bf(float f) {
    uint32_t u = __builtin_bit_cast(uint32_t, f);
    u += 0x7FFFu + ((u >> 16) & 1u);
    uint16_t b = (uint16_t)(u >> 16);
    return __builtin_bit_cast(bf16, b);
}

// ---------------- stem: h[t,o] = sum_c stem_w[o,c] * x[b,c,s];  + ss for rl[0]
__global__ __launch_bounds__(256) void k_stem(
    const float* __restrict__ x, const float* __restrict__ w,
    float* __restrict__ h, float* __restrict__ ss_out)
{
    __shared__ bf16 As[64*40];
    __shared__ bf16 Bs[64*40];
    __shared__ float Cs[64*66];
    const int t0 = blockIdx.x*64, n0 = blockIdx.y*64;
    const int b = t0 >> 8, s0 = t0 & 255;
    const int tid = threadIdx.x, lane = tid & 63, wv_ = tid >> 6;
    const int wm = wv_ >> 1, wn = wv_ & 1;
    const int rr = tid >> 2, cc8 = (tid & 3)*8;
    f32x4 acc[2][2] = {};
    for (int k0 = 0; k0 < NC; k0 += 32) {
        #pragma unroll
        for (int e = 0; e < 8; ++e) {
            int idx = tid + e*256;
            int c = idx >> 6, r = idx & 63;
            As[r*40 + c] = f2bf(x[(size_t)(b*NC + k0 + c)*NS + s0 + r]);
        }
        {
            const float* src = &w[(size_t)(n0 + rr)*NC + k0 + cc8];
            bf16x8 t;
            #pragma unroll
            for (int i = 0; i < 8; ++i) t[i] = f2bf(src[i]);
            *(bf16x8*)&Bs[rr*40 + cc8] = t;
        }
        __syncthreads();
        const int fr = lane & 15, kg = (lane >> 4)*8;
        bf16x8 a0 = *(const bf16x8*)&As[(wm*32 + fr)*40 + kg];
        bf16x8 a1 = *(const bf16x8*)&As[(wm*32 + 16 + fr)*40 + kg];
        bf16x8 b0 = *(const bf16x8*)&Bs[(wn*32 + fr)*40 + kg];
        bf16x8 b1 = *(const bf16x8*)&Bs[(wn*32 + 16 + fr)*40 + kg];
        acc[0][0] = __builtin_amdgcn_mfma_f32_16x16x32_bf16(a0, b0, acc[0][0], 0,0,0);
        acc[0][1] = __builtin_amdgcn_mfma_f32_16x16x32_bf16(a0, b1, acc[0][1], 0,0,0);
        acc[1][0] = __builtin_amdgcn_mfma_f32_16x16x32_bf16(a1, b0, acc[1][0], 0,0,0);
        acc[1][1] = __builtin_amdgcn_mfma_f32_16x16x32_bf16(a1, b1, acc[1][1], 0,0,0);
        __syncthreads();
    }
    const int row4 = (lane >> 4)*4, col = lane & 15;
    #pragma unroll
    for (int mi = 0; mi < 2; ++mi)
      #pragma unroll
      for (int ni = 0; ni < 2; ++ni)
        #pragma unroll
        for (int r = 0; r < 4; ++r)
            Cs[(wm*32 + mi*16 + row4 + r)*66 + wn*32 + ni*16 + col] = acc[mi][ni][r];
    __syncthreads();
    const int c16 = (tid & 3)*16;
    float ssum = 0.f;
    float* dst = &h[(size_t)(t0 + rr)*NH + n0 + c16];
    #pragma unroll
    for (int i = 0; i < 16; ++i) {
        float v = Cs[rr*66 + c16 + i];
        dst[i] = v;
        ssum += v*v;
    }
    ssum += __shfl_xor(ssum, 1, 64);
    ssum += __shfl_xor(ssum, 2, 64);
    if ((tid & 3) == 0) atomicAdd(&ss_out[t0 + rr], ssum);
}

// ---------------- unified local/global mix
// STR=1  (local):  tokens base+k,   k in [0,16), base = b*256 + g*16
// STR=16 (global): tokens base+16k, k in [0,16), base = b*256 + g
// out[p] = raw[p] + alpha*rms_w[c]*sum_k W[c][p*16+k]*u[k],  u[k]=raw[k]*rstd[k]
template<int STR>
__global__ __launch_bounds__(256) void k_mix(
    float* __restrict__ h, const float* __restrict__ ss_in,
    const float* __restrict__ w, const float* __restrict__ rmsw,
    const float* __restrict__ alpha_p, float* __restrict__ ss_out)
{
    __shared__ float raw[16*64];
    __shared__ float rstdL[16];
    const int b = blockIdx.x >> 4, g = blockIdx.x & 15, c0 = blockIdx.y*64;
    const int tid = threadIdx.x;
    const int c = tid & 63, pq = tid >> 6;
    const int base = b*NS + (STR == 1 ? g*16 : g);
    if (tid < 16) rstdL[tid] = rsqrtf(ss_in[base + tid*STR]*(1.f/NH) + EPSF);
    #pragma unroll
    for (int e = 0; e < 4; ++e) {
        int idx = tid + e*256;
        int j = idx >> 6, cc = idx & 63;
        raw[j*64 + cc] = h[(size_t)(base + j*STR)*NH + c0 + cc];
    }
    __syncthreads();
    float u[16];
    #pragma unroll
    for (int j = 0; j < 16; ++j) u[j] = raw[j*64 + c] * rstdL[j];
    const float al = *alpha_p;
    const float rc = rmsw[c0 + c] * al;
    const float* wrow = &w[(size_t)(c0 + c)*256 + pq*64];
    float hn[4];
    #pragma unroll
    for (int q = 0; q < 4; ++q) {
        float acc = 0.f;
        #pragma unroll
        for (int jv = 0; jv < 4; ++jv) {
            float4 w4 = *(const float4*)&wrow[q*16 + jv*4];
            acc += w4.x*u[jv*4+0] + w4.y*u[jv*4+1] + w4.z*u[jv*4+2] + w4.w*u[jv*4+3];
        }
        const int p = pq*4 + q;
        hn[q] = raw[p*64 + c] + rc*acc;
        h[(size_t)(base + p*STR)*NH + c0 + c] = hn[q];
    }
    #pragma unroll
    for (int q = 0; q < 4; ++q) {
        float ssum = hn[q]*hn[q];
        ssum += __shfl_xor(ssum, 1, 64);
        ssum += __shfl_xor(ssum, 2, 64);
        ssum += __shfl_xor(ssum, 4, 64);
        ssum += __shfl_xor(ssum, 8, 64);
        ssum += __shfl_xor(ssum, 16, 64);
        ssum += __shfl_xor(ssum, 32, 64);
        if (c == 0) atomicAdd(&ss_out[base + (pq*4 + q)*STR], ssum);
    }
}

// ---------------- mlp in: g = silu(wv . norm(h)) * (wg . norm(h))   (bf16 out)
__global__ __launch_bounds__(256) void k_mlp_in(
    const float* __restrict__ h, const float* __restrict__ ss_in,
    const float* __restrict__ rmsw, const float* __restrict__ wvl,
    const float* __restrict__ wgl, bf16* __restrict__ g)
{
    __shared__ bf16 As[64*40], Bs1[64*40], Bs3[64*40];
    __shared__ float rstdA[64], rw[NH];
    __shared__ bf16 Gs[64*72];
    const int t0 = blockIdx.x*64, n0 = blockIdx.y*64;
    const int tid = threadIdx.x, lane = tid & 63, wv_ = tid >> 6;
    const int wm = wv_ >> 1, wn = wv_ & 1;
    const int rr = tid >> 2, cc8 = (tid & 3)*8;
    if (tid < 64) rstdA[tid] = rsqrtf(ss_in[t0 + tid]*(1.f/NH) + EPSF);
    rw[tid] = rmsw[tid]; rw[tid + 256] = rmsw[tid + 256];
    __syncthreads();
    f32x4 acc1[2][2] = {}, acc3[2][2] = {};
    for (int k0 = 0; k0 < NH; k0 += 32) {
        {
            const float* src = &h[(size_t)(t0 + rr)*NH + k0 + cc8];
            float sc = rstdA[rr];
            bf16x8 t;
            #pragma unroll
            for (int i = 0; i < 8; ++i) t[i] = f2bf(src[i]*sc*rw[k0 + cc8 + i]);
            *(bf16x8*)&As[rr*40 + cc8] = t;
        }
        {
            const float* s1 = &wvl[(size_t)(n0 + rr)*NH + k0 + cc8];
            const float* s3 = &wgl[(size_t)(n0 + rr)*NH + k0 + cc8];
            bf16x8 t1, t3;
            #pragma unroll
            for (int i = 0; i < 8; ++i) { t1[i] = f2bf(s1[i]); t3[i] = f2bf(s3[i]); }
            *(bf16x8*)&Bs1[rr*40 + cc8] = t1;
            *(bf16x8*)&Bs3[rr*40 + cc8] = t3;
        }
        __syncthreads();
        const int fr = lane & 15, kg = (lane >> 4)*8;
        bf16x8 a0 = *(const bf16x8*)&As[(wm*32 + fr)*40 + kg];
        bf16x8 a1 = *(const bf16x8*)&As[(wm*32 + 16 + fr)*40 + kg];
        bf16x8 u0 = *(const bf16x8*)&Bs1[(wn*32 + fr)*40 + kg];
        bf16x8 u1 = *(const bf16x8*)&Bs1[(wn*32 + 16 + fr)*40 + kg];
        bf16x8 v0 = *(const bf16x8*)&Bs3[(wn*32 + fr)*40 + kg];
        bf16x8 v1 = *(const bf16x8*)&Bs3[(wn*32 + 16 + fr)*40 + kg];
        acc1[0][0] = __builtin_amdgcn_mfma_f32_16x16x32_bf16(a0, u0, acc1[0][0], 0,0,0);
        acc1[0][1] = __builtin_amdgcn_mfma_f32_16x16x32_bf16(a0, u1, acc1[0][1], 0,0,0);
        acc1[1][0] = __builtin_amdgcn_mfma_f32_16x16x32_bf16(a1, u0, acc1[1][0], 0,0,0);
        acc1[1][1] = __builtin_amdgcn_mfma_f32_16x16x32_bf16(a1, u1, acc1[1][1], 0,0,0);
        acc3[0][0] = __builtin_amdgcn_mfma_f32_16x16x32_bf16(a0, v0, acc3[0][0], 0,0,0);
        acc3[0][1] = __builtin_amdgcn_mfma_f32_16x16x32_bf16(a0, v1, acc3[0][1], 0,0,0);
        acc3[1][0] = __builtin_amdgcn_mfma_f32_16x16x32_bf16(a1, v0, acc3[1][0], 0,0,0);
        acc3[1][1] = __builtin_amdgcn_mfma_f32_16x16x32_bf16(a1, v1, acc3[1][1], 0,0,0);
        __syncthreads();
    }
    const int row4 = (lane >> 4)*4, col = lane & 15;
    #pragma unroll
    for (int mi = 0; mi < 2; ++mi)
      #pragma unroll
      for (int ni = 0; ni < 2; ++ni)
        #pragma unroll
        for (int r = 0; r < 4; ++r) {
            float xv = acc1[mi][ni][r];
            float gl = (xv / (1.f + __expf(-xv))) * acc3[mi][ni][r];
            Gs[(wm*32 + mi*16 + row4 + r)*72 + wn*32 + ni*16 + col] = f2bf(gl);
        }
    __syncthreads();
    const int c16 = (tid & 3)*16;
    bf16x8 o0 = *(const bf16x8*)&Gs[rr*72 + c16];
    bf16x8 o1 = *(const bf16x8*)&Gs[rr*72 + c16 + 8];
    *(bf16x8*)&g[(size_t)(t0 + rr)*NG + n0 + c16] = o0;
    *(bf16x8*)&g[(size_t)(t0 + rr)*NG + n0 + c16 + 8] = o1;
}

// ---------------- mlp out: h += alpha * (wo . g); + ss for next norm
__global__ __launch_bounds__(256) void k_mlp_out(
    const bf16* __restrict__ g, const float* __restrict__ wol,
    const float* __restrict__ alpha_p, float* __restrict__ h,
    float* __restrict__ ss_out)
{
    __shared__ bf16 As[64*40], Bs[64*40];
    __shared__ float Cs[64*66];
    const int t0 = blockIdx.x*64, n0 = blockIdx.y*64;
    const int tid = threadIdx.x, lane = tid & 63, wv_ = tid >> 6;
    const int wm = wv_ >> 1, wn = wv_ & 1;
    const int rr = tid >> 2, cc8 = (tid & 3)*8;
    f32x4 acc[2][2] = {};
    for (int k0 = 0; k0 < NG; k0 += 32) {
        *(bf16x8*)&As[rr*40 + cc8] = *(const bf16x8*)&g[(size_t)(t0 + rr)*NG + k0 + cc8];
        {
            const float* src = &wol[(size_t)(n0 + rr)*NG + k0 + cc8];
            bf16x8 t;
            #pragma unroll
            for (int i = 0; i < 8; ++i) t[i] = f2bf(src[i]);
            *(bf16x8*)&Bs[rr*40 + cc8] = t;
        }
        __syncthreads();
        const int fr = lane & 15, kg = (lane >> 4)*8;
        bf16x8 a0 = *(const bf16x8*)&As[(wm*32 + fr)*40 + kg];
        bf16x8 a1 = *(const bf16x8*)&As[(wm*32 + 16 + fr)*40 + kg];
        bf16x8 b0 = *(const bf16x8*)&Bs[(wn*32 + fr)*40 + kg];
        bf16x8 b1 = *(const bf16x8*)&Bs[(wn*32 + 16 + fr)*40 + kg];
        acc[0][0] = __builtin_amdgcn_mfma_f32_16x16x32_bf16(a0, b0, acc[0][0], 0,0,0);
        acc[0][1] = __builtin_amdgcn_mfma_f32_16x16x32_bf16(a0, b1, acc[0][1], 0,0,0);
        acc[1][0] = __builtin_amdgcn_mfma_f32_16x16x32_bf16(a1, b0, acc[1][0], 0,0,0);
        acc[1][1] = __builtin_amdgcn_mfma_f32_16x16x32_bf16(a1, b1, acc[1][1], 0,0,0);
        __syncthreads();
    }
    const int row4 = (lane >> 4)*4, col = lane & 15;
    #pragma unroll
    for (int mi = 0; mi < 2; ++mi)
      #pragma unroll
      for (int ni = 0; ni < 2; ++ni)
        #pragma unroll
        for (int r = 0; r < 4; ++r)
            Cs[(wm*32 + mi*16 + row4 + r)*66 + wn*32 + ni*16 + col] = acc[mi][ni][r];
    __syncthreads();
    const float am = *alpha_p;
    const int c16 = (tid & 3)*16;
    float* dst = &h[(size_t)(t0 + rr)*NH + n0 + c16];
    float ssum = 0.f;
    #pragma unroll
    for (int i = 0; i < 16; ++i) {
        float hn = dst[i] + am * Cs[rr*66 + c16 + i];
        dst[i] = hn;
        ssum += hn*hn;
    }
    ssum += __shfl_xor(ssum, 1, 64);
    ssum += __shfl_xor(ssum, 2, 64);
    if ((tid & 3) == 0) atomicAdd(&ss_out[t0 + rr], ssum);
}

// ---------------- head: logits[b,v,s] = scale * head_w . (norm(h)*head_rms)
__global__ __launch_bounds__(256) void k_head(
    const float* __restrict__ h, const float* __restrict__ ss_in,
    const float* __restrict__ rmsw, const float* __restrict__ hw,
    const float* __restrict__ scale_p, float* __restrict__ out)
{
    __shared__ bf16 As[64*40], Bs[64*40];
    __shared__ float Ls[64*66];
    __shared__ float rstdA[64], rw[NH];
    const int t0 = blockIdx.x*64, n0 = blockIdx.y*64;
    const int tid = threadIdx.x, lane = tid & 63, wv_ = tid >> 6;
    const int wm = wv_ >> 1, wn = wv_ & 1;
    const int rr = tid >> 2, cc8 = (tid & 3)*8;
    if (tid < 64) rstdA[tid] = rsqrtf(ss_in[t0 + tid]*(1.f/NH) + EPSF);
    rw[tid] = rmsw[tid]; rw[tid + 256] = rmsw[tid + 256];
    __syncthreads();
    f32x4 acc[2][2] = {};
    for (int k0 = 0; k0 < NH; k0 += 32) {
        {
            const float* src = &h[(size_t)(t0 + rr)*NH + k0 + cc8];
            float sc = rstdA[rr];
            bf16x8 t;
            #pragma unroll
            for (int i = 0; i < 8; ++i) t[i] = f2bf(src[i]*sc*rw[k0 + cc8 + i]);
            *(bf16x8*)&As[rr*40 + cc8] = t;
        }
        {
            const float* src = &hw[(size_t)(n0 + rr)*NH + k0 + cc8];
            bf16x8 t;
            #pragma unroll
            for (int i = 0; i < 8; ++i) t[i] = f2bf(src[i]);
            *(bf16x8*)&Bs[rr*40 + cc8] = t;
        }
        __syncthreads();
        const int fr = lane & 15, kg = (lane >> 4)*8;
        bf16x8 a0 = *(const bf16x8*)&As[(wm*32 + fr)*40 + kg];
        bf16x8 a1 = *(const bf16x8*)&As[(wm*32 + 16 + fr)*40 + kg];
        bf16x8 b0 = *(const bf16x8*)&Bs[(wn*32 + fr)*40 + kg];
        bf16x8 b1 = *(const bf16x8*)&Bs[(wn*32 + 16 + fr)*40 + kg];
        acc[0][0] = __builtin_amdgcn_mfma_f32_16x16x32_bf16(a0, b0, acc[0][0], 0,0,0);
        acc[0][1] = __builtin_amdgcn_mfma_f32_16x16x32_bf16(a0, b1, acc[0][1], 0,0,0);
        acc[1][0] = __builtin_amdgcn_mfma_f32_16x16x32_bf16(a1, b0, acc[1][0], 0,0,0);
        acc[1][1] = __builtin_amdgcn_mfma_f32_16x16x32_bf16(a1, b1, acc[1][1], 0,0,0);
        __syncthreads();
    }
    const float sc = *scale_p;
    const int row4 = (lane >> 4)*4, col = lane & 15;
    #pragma unroll
    for (int mi = 0; mi < 2; ++mi)
      #pragma unroll
      for (int ni = 0; ni < 2; ++ni)
        #pragma unroll
        for (int r = 0; r < 4; ++r)
            Ls[(wm*32 + mi*16 + row4 + r)*66 + wn*32 + ni*16 + col] = sc * acc[mi][ni][r];
    __syncthreads();
    const int vv = tid >> 2, s16 = (tid & 3)*16;
    const int b = t0 >> 8, s0 = t0 & 255;
    float* dst = &out[((size_t)(b*NV + n0 + vv))*NS + s0 + s16];
    #pragma unroll
    for (int i = 0; i < 16; ++i) dst[i] = Ls[(s16 + i)*66 + vv];
}

extern "C" void kernel_launch(void* const* d_in, const int* in_sizes, int n_in,
                              void* d_out, int out_size, void* d_ws, size_t ws_size,
                              hipStream_t stream) {
    const float* x          = (const float*)d_in[0];
    const float* stem_w     = (const float*)d_in[1];
    const float* rms_local  = (const float*)d_in[2];
    const float* rms_global = (const float*)d_in[3];
    const float* rms_ffn    = (const float*)d_in[4];
    const float* alpha_local  = (const float*)d_in[5];
    const float* alpha_global = (const float*)d_in[6];
    const float* alpha_mlp    = (const float*)d_in[7];
    const float* w_local    = (const float*)d_in[8];
    const float* w_global   = (const float*)d_in[9];
    const float* wv         = (const float*)d_in[10];
    const float* wg         = (const float*)d_in[11];
    const float* wo         = (const float*)d_in[12];
    const float* head_rms   = (const float*)d_in[13];
    const float* head_scale = (const float*)d_in[14];
    const float* head_w     = (const float*)d_in[15];
    float* out = (float*)d_out;

    char* ws = (char*)d_ws;
    float* h  = (float*)ws;                                   // 4 MB
    bf16*  g  = (bf16*)(ws + (size_t)4*1024*1024);            // 4 MB
    float* ss = (float*)(ws + (size_t)8*1024*1024);           // 73 * 2048 * 4
    float* ss_rl = ss;
    float* ss_rg = ss + 24*NT;
    float* ss_rf = ss + 48*NT;
    float* ss_hd = ss + 72*NT;

    hipMemsetAsync(ss, 0, (size_t)73*NT*sizeof(float), stream);

    k_stem<<<dim3(32, 8), 256, 0, stream>>>(x, stem_w, h, ss_rl);
    for (int l = 0; l < NL; ++l) {
        k_mix<1><<<dim3(128, 8), 256, 0, stream>>>(
            h, ss_rl + l*NT, w_local + (size_t)l*NH*256,
            rms_local + l*NH, alpha_local + l, ss_rg + l*NT);
        k_mix<16><<<dim3(128, 8), 256, 0, stream>>>(
            h, ss_rg + l*NT, w_global + (size_t)l*NH*256,
            rms_global + l*NH, alpha_global + l, ss_rf + l*NT);
        k_mlp_in<<<dim3(32, 16), 256, 0, stream>>>(
            h, ss_rf + l*NT, rms_ffn + l*NH,
            wv + (size_t)l*NG*NH, wg + (size_t)l*NG*NH, g);
        float* ssn = (l == NL-1) ? ss_hd : (ss_rl + (l+1)*NT);
        k_mlp_out<<<dim3(32, 8), 256, 0, stream>>>(
            g, wo + (size_t)l*NH*NG, alpha_mlp + l, h, ssn);
    }
    k_head<<<dim3(32, 4), 256, 0, stream>>>(h, ss_hd, head_rms, head_w, head_scale, out);
}

// Round 4
// 1455.050 us; speedup vs baseline: 1.6751x; 1.2177x over previous
//
#include <hip/hip_runtime.h>
#include <hip/hip_bf16.h>
#include <stdint.h>

#define NB 8
#define NS 256
#define NH 512
#define NG 1024
#define NV 256
#define NL 24
#define NC 320
#define NT 2048
#define EPSF 1e-5f

typedef __bf16 bf16;
typedef bf16 bf16x8 __attribute__((ext_vector_type(8)));
typedef float f32x4 __attribute__((ext_vector_type(4)));

__device__ __forceinline__ bf16 f2bf(float f) {
    uint32_t u = __builtin_bit_cast(uint32_t, f);
    u += 0x7FFFu + ((u >> 16) & 1u);
    uint16_t b = (uint16_t)(u >> 16);
    return __builtin_bit_cast(bf16, b);
}

// async global->LDS, 16B per lane; lds dst = wave-uniform base + lane*16B
__device__ __forceinline__ void gload16(const void* g, void* l) {
    __builtin_amdgcn_global_load_lds(
        (const __attribute__((address_space(1))) void*)g,
        (__attribute__((address_space(3))) void*)l,
        16, 0, 0);
}

// ---------------- f32 -> bf16 bulk convert (n8 = elems/8)
__global__ __launch_bounds__(256) void k_cvt(
    const float* __restrict__ src, bf16* __restrict__ dst, int n8)
{
    int i = blockIdx.x*256 + threadIdx.x;
    const int stride = gridDim.x*256;
    for (; i < n8; i += stride) {
        const float* s = src + (size_t)i*8;
        bf16x8 t;
        #pragma unroll
        for (int j = 0; j < 8; ++j) t[j] = f2bf(s[j]);
        *(bf16x8*)&dst[(size_t)i*8] = t;
    }
}

// ---------------- x[b][c][s] f32 -> xT[b*256+s][c] bf16 (64x64 LDS transpose)
__global__ __launch_bounds__(256) void k_trx(
    const float* __restrict__ x, bf16* __restrict__ xT)
{
    __shared__ bf16 Ls[64*72];
    const int s0 = blockIdx.x*64, c0 = blockIdx.y*64, b = blockIdx.z;
    const int tid = threadIdx.x;
    #pragma unroll
    for (int e = 0; e < 16; ++e) {
        int idx = tid + e*256;
        int c = idx >> 6, s = idx & 63;
        Ls[s*72 + c] = f2bf(x[(size_t)(b*NC + c0 + c)*NS + s0 + s]);
    }
    __syncthreads();
    #pragma unroll
    for (int e = 0; e < 2; ++e) {
        int idx = tid + e*256;           // 512 = 64 rows x 8 chunks
        int s = idx >> 3, ch = idx & 7;
        *(bf16x8*)&xT[(size_t)(b*NS + s0 + s)*NC + c0 + ch*8] =
            *(const bf16x8*)&Ls[s*72 + ch*8];
    }
}

// ---------------- stem GEMM: h[t,o] = xT[t,:] . wb[o,:]; + ss for rl[0]
__global__ __launch_bounds__(256) void k_stem_b(
    const bf16* __restrict__ xT, const bf16* __restrict__ wb,
    float* __restrict__ h, float* __restrict__ ss_out)
{
    __shared__ bf16 As[64*32], Bs[64*32];
    __shared__ float Cs[64*66];
    const int t0 = blockIdx.x*64, n0 = blockIdx.y*64;
    const int tid = threadIdx.x, lane = tid & 63, wv_ = tid >> 6;
    const int wm = wv_ >> 1, wn = wv_ & 1;
    const int srow = wv_*16 + (lane >> 2), sch = (lane & 3)*8;
    f32x4 acc[2][2] = {};
    for (int k0 = 0; k0 < NC; k0 += 32) {
        gload16(xT + (size_t)(t0 + srow)*NC + k0 + sch, As + wv_*512);
        gload16(wb + (size_t)(n0 + srow)*NC + k0 + sch, Bs + wv_*512);
        __syncthreads();
        const int fr = lane & 15, kg = (lane >> 4)*8;
        bf16x8 a0 = *(const bf16x8*)&As[(wm*32 + fr)*32 + kg];
        bf16x8 a1 = *(const bf16x8*)&As[(wm*32 + 16 + fr)*32 + kg];
        bf16x8 b0 = *(const bf16x8*)&Bs[(wn*32 + fr)*32 + kg];
        bf16x8 b1 = *(const bf16x8*)&Bs[(wn*32 + 16 + fr)*32 + kg];
        acc[0][0] = __builtin_amdgcn_mfma_f32_16x16x32_bf16(a0, b0, acc[0][0], 0,0,0);
        acc[0][1] = __builtin_amdgcn_mfma_f32_16x16x32_bf16(a0, b1, acc[0][1], 0,0,0);
        acc[1][0] = __builtin_amdgcn_mfma_f32_16x16x32_bf16(a1, b0, acc[1][0], 0,0,0);
        acc[1][1] = __builtin_amdgcn_mfma_f32_16x16x32_bf16(a1, b1, acc[1][1], 0,0,0);
        __syncthreads();
    }
    const int row4 = (lane >> 4)*4, col = lane & 15;
    #pragma unroll
    for (int mi = 0; mi < 2; ++mi)
      #pragma unroll
      for (int ni = 0; ni < 2; ++ni)
        #pragma unroll
        for (int r = 0; r < 4; ++r)
            Cs[(wm*32 + mi*16 + row4 + r)*66 + wn*32 + ni*16 + col] = acc[mi][ni][r];
    __syncthreads();
    const int rr = tid >> 2, c16 = (tid & 3)*16;
    float ssum = 0.f;
    float* dst = &h[(size_t)(t0 + rr)*NH + n0 + c16];
    #pragma unroll
    for (int i = 0; i < 16; ++i) {
        float v = Cs[rr*66 + c16 + i];
        dst[i] = v;
        ssum += v*v;
    }
    ssum += __shfl_xor(ssum, 1, 64);
    ssum += __shfl_xor(ssum, 2, 64);
    if ((tid & 3) == 0) atomicAdd(&ss_out[t0 + rr], ssum);
}

// ---------------- unified local/global mix (unchanged, round-3 verified)
template<int STR>
__global__ __launch_bounds__(256) void k_mix(
    float* __restrict__ h, const float* __restrict__ ss_in,
    const float* __restrict__ w, const float* __restrict__ rmsw,
    const float* __restrict__ alpha_p, float* __restrict__ ss_out)
{
    __shared__ float raw[16*64];
    __shared__ float rstdL[16];
    const int b = blockIdx.x >> 4, g = blockIdx.x & 15, c0 = blockIdx.y*64;
    const int tid = threadIdx.x;
    const int c = tid & 63, pq = tid >> 6;
    const int base = b*NS + (STR == 1 ? g*16 : g);
    if (tid < 16) rstdL[tid] = rsqrtf(ss_in[base + tid*STR]*(1.f/NH) + EPSF);
    #pragma unroll
    for (int e = 0; e < 4; ++e) {
        int idx = tid + e*256;
        int j = idx >> 6, cc = idx & 63;
        raw[j*64 + cc] = h[(size_t)(base + j*STR)*NH + c0 + cc];
    }
    __syncthreads();
    float u[16];
    #pragma unroll
    for (int j = 0; j < 16; ++j) u[j] = raw[j*64 + c] * rstdL[j];
    const float al = *alpha_p;
    const float rc = rmsw[c0 + c] * al;
    const float* wrow = &w[(size_t)(c0 + c)*256 + pq*64];
    float hn[4];
    #pragma unroll
    for (int q = 0; q < 4; ++q) {
        float acc = 0.f;
        #pragma unroll
        for (int jv = 0; jv < 4; ++jv) {
            float4 w4 = *(const float4*)&wrow[q*16 + jv*4];
            acc += w4.x*u[jv*4+0] + w4.y*u[jv*4+1] + w4.z*u[jv*4+2] + w4.w*u[jv*4+3];
        }
        const int p = pq*4 + q;
        hn[q] = raw[p*64 + c] + rc*acc;
        h[(size_t)(base + p*STR)*NH + c0 + c] = hn[q];
    }
    #pragma unroll
    for (int q = 0; q < 4; ++q) {
        float ssum = hn[q]*hn[q];
        ssum += __shfl_xor(ssum, 1, 64);
        ssum += __shfl_xor(ssum, 2, 64);
        ssum += __shfl_xor(ssum, 4, 64);
        ssum += __shfl_xor(ssum, 8, 64);
        ssum += __shfl_xor(ssum, 16, 64);
        ssum += __shfl_xor(ssum, 32, 64);
        if (c == 0) atomicAdd(&ss_out[base + (pq*4 + q)*STR], ssum);
    }
}

// ---------------- norm: a[t,c] = bf16( h[t,c] * rstd(t) * rmsw[c] )
__global__ __launch_bounds__(256) void k_norm(
    const float* __restrict__ h, const float* __restrict__ ss_in,
    const float* __restrict__ rmsw, bf16* __restrict__ a)
{
    const int t = blockIdx.x*4 + (threadIdx.x >> 6);
    const int c8 = (threadIdx.x & 63)*8;
    const float rstd = rsqrtf(ss_in[t]*(1.f/NH) + EPSF);
    const float* src = &h[(size_t)t*NH + c8];
    float4 h0 = *(const float4*)&src[0];
    float4 h1 = *(const float4*)&src[4];
    float4 w0 = *(const float4*)&rmsw[c8];
    float4 w1 = *(const float4*)&rmsw[c8 + 4];
    bf16x8 o;
    o[0] = f2bf(h0.x*rstd*w0.x); o[1] = f2bf(h0.y*rstd*w0.y);
    o[2] = f2bf(h0.z*rstd*w0.z); o[3] = f2bf(h0.w*rstd*w0.w);
    o[4] = f2bf(h1.x*rstd*w1.x); o[5] = f2bf(h1.y*rstd*w1.y);
    o[6] = f2bf(h1.z*rstd*w1.z); o[7] = f2bf(h1.w*rstd*w1.w);
    *(bf16x8*)&a[(size_t)t*NH + c8] = o;
}

// ---------------- mlp in: g = silu(wv . a) * (wg . a)   (bf16 out)
template<bool PRE>
__global__ __launch_bounds__(256) void k_mlp_in(
    const bf16* __restrict__ a, const void* __restrict__ wv_p,
    const void* __restrict__ wg_p, bf16* __restrict__ g)
{
    __shared__ bf16 As[64*32], Bs1[64*32], Bs3[64*32];
    __shared__ bf16 Gs[64*72];
    const int t0 = blockIdx.x*64, n0 = blockIdx.y*64;
    const int tid = threadIdx.x, lane = tid & 63, wv_ = tid >> 6;
    const int wm = wv_ >> 1, wn = wv_ & 1;
    const int srow = wv_*16 + (lane >> 2), sch = (lane & 3)*8;
    f32x4 acc1[2][2] = {}, acc3[2][2] = {};
    for (int k0 = 0; k0 < NH; k0 += 32) {
        gload16(a + (size_t)(t0 + srow)*NH + k0 + sch, As + wv_*512);
        if constexpr (PRE) {
            gload16((const bf16*)wv_p + (size_t)(n0 + srow)*NH + k0 + sch, Bs1 + wv_*512);
            gload16((const bf16*)wg_p + (size_t)(n0 + srow)*NH + k0 + sch, Bs3 + wv_*512);
        } else {
            const int r = tid >> 2, c8 = (tid & 3)*8;
            const float* s1 = (const float*)wv_p + (size_t)(n0 + r)*NH + k0 + c8;
            const float* s3 = (const float*)wg_p + (size_t)(n0 + r)*NH + k0 + c8;
            bf16x8 t1, t3;
            #pragma unroll
            for (int i = 0; i < 8; ++i) { t1[i] = f2bf(s1[i]); t3[i] = f2bf(s3[i]); }
            *(bf16x8*)&Bs1[r*32 + c8] = t1;
            *(bf16x8*)&Bs3[r*32 + c8] = t3;
        }
        __syncthreads();
        const int fr = lane & 15, kg = (lane >> 4)*8;
        bf16x8 a0 = *(const bf16x8*)&As[(wm*32 + fr)*32 + kg];
        bf16x8 a1 = *(const bf16x8*)&As[(wm*32 + 16 + fr)*32 + kg];
        bf16x8 u0 = *(const bf16x8*)&Bs1[(wn*32 + fr)*32 + kg];
        bf16x8 u1 = *(const bf16x8*)&Bs1[(wn*32 + 16 + fr)*32 + kg];
        bf16x8 v0 = *(const bf16x8*)&Bs3[(wn*32 + fr)*32 + kg];
        bf16x8 v1 = *(const bf16x8*)&Bs3[(wn*32 + 16 + fr)*32 + kg];
        acc1[0][0] = __builtin_amdgcn_mfma_f32_16x16x32_bf16(a0, u0, acc1[0][0], 0,0,0);
        acc1[0][1] = __builtin_amdgcn_mfma_f32_16x16x32_bf16(a0, u1, acc1[0][1], 0,0,0);
        acc1[1][0] = __builtin_amdgcn_mfma_f32_16x16x32_bf16(a1, u0, acc1[1][0], 0,0,0);
        acc1[1][1] = __builtin_amdgcn_mfma_f32_16x16x32_bf16(a1, u1, acc1[1][1], 0,0,0);
        acc3[0][0] = __builtin_amdgcn_mfma_f32_16x16x32_bf16(a0, v0, acc3[0][0], 0,0,0);
        acc3[0][1] = __builtin_amdgcn_mfma_f32_16x16x32_bf16(a0, v1, acc3[0][1], 0,0,0);
        acc3[1][0] = __builtin_amdgcn_mfma_f32_16x16x32_bf16(a1, v0, acc3[1][0], 0,0,0);
        acc3[1][1] = __builtin_amdgcn_mfma_f32_16x16x32_bf16(a1, v1, acc3[1][1], 0,0,0);
        __syncthreads();
    }
    const int row4 = (lane >> 4)*4, col = lane & 15;
    #pragma unroll
    for (int mi = 0; mi < 2; ++mi)
      #pragma unroll
      for (int ni = 0; ni < 2; ++ni)
        #pragma unroll
        for (int r = 0; r < 4; ++r) {
            float xv = acc1[mi][ni][r];
            float gl = (xv / (1.f + __expf(-xv))) * acc3[mi][ni][r];
            Gs[(wm*32 + mi*16 + row4 + r)*72 + wn*32 + ni*16 + col] = f2bf(gl);
        }
    __syncthreads();
    const int rr = tid >> 2, c16 = (tid & 3)*16;
    bf16x8 o0 = *(const bf16x8*)&Gs[rr*72 + c16];
    bf16x8 o1 = *(const bf16x8*)&Gs[rr*72 + c16 + 8];
    *(bf16x8*)&g[(size_t)(t0 + rr)*NG + n0 + c16] = o0;
    *(bf16x8*)&g[(size_t)(t0 + rr)*NG + n0 + c16 + 8] = o1;
}

// ---------------- mlp out: h += alpha * (wo . g); + ss for next norm
template<bool PRE>
__global__ __launch_bounds__(256) void k_mlp_out(
    const bf16* __restrict__ g, const void* __restrict__ wo_p,
    const float* __restrict__ alpha_p, float* __restrict__ h,
    float* __restrict__ ss_out)
{
    __shared__ bf16 As[64*32], Bs[64*32];
    __shared__ float Cs[64*66];
    const int t0 = blockIdx.x*64, n0 = blockIdx.y*64;
    const int tid = threadIdx.x, lane = tid & 63, wv_ = tid >> 6;
    const int wm = wv_ >> 1, wn = wv_ & 1;
    const int srow = wv_*16 + (lane >> 2), sch = (lane & 3)*8;
    f32x4 acc[2][2] = {};
    for (int k0 = 0; k0 < NG; k0 += 32) {
        gload16(g + (size_t)(t0 + srow)*NG + k0 + sch, As + wv_*512);
        if constexpr (PRE) {
            gload16((const bf16*)wo_p + (size_t)(n0 + srow)*NG + k0 + sch, Bs + wv_*512);
        } else {
            const int r = tid >> 2, c8 = (tid & 3)*8;
            const float* src = (const float*)wo_p + (size_t)(n0 + r)*NG + k0 + c8;
            bf16x8 t;
            #pragma unroll
            for (int i = 0; i < 8; ++i) t[i] = f2bf(src[i]);
            *(bf16x8*)&Bs[r*32 + c8] = t;
        }
        __syncthreads();
        const int fr = lane & 15, kg = (lane >> 4)*8;
        bf16x8 a0 = *(const bf16x8*)&As[(wm*32 + fr)*32 + kg];
        bf16x8 a1 = *(const bf16x8*)&As[(wm*32 + 16 + fr)*32 + kg];
        bf16x8 b0 = *(const bf16x8*)&Bs[(wn*32 + fr)*32 + kg];
        bf16x8 b1 = *(const bf16x8*)&Bs[(wn*32 + 16 + fr)*32 + kg];
        acc[0][0] = __builtin_amdgcn_mfma_f32_16x16x32_bf16(a0, b0, acc[0][0], 0,0,0);
        acc[0][1] = __builtin_amdgcn_mfma_f32_16x16x32_bf16(a0, b1, acc[0][1], 0,0,0);
        acc[1][0] = __builtin_amdgcn_mfma_f32_16x16x32_bf16(a1, b0, acc[1][0], 0,0,0);
        acc[1][1] = __builtin_amdgcn_mfma_f32_16x16x32_bf16(a1, b1, acc[1][1], 0,0,0);
        __syncthreads();
    }
    const int row4 = (lane >> 4)*4, col = lane & 15;
    #pragma unroll
    for (int mi = 0; mi < 2; ++mi)
      #pragma unroll
      for (int ni = 0; ni < 2; ++ni)
        #pragma unroll
        for (int r = 0; r < 4; ++r)
            Cs[(wm*32 + mi*16 + row4 + r)*66 + wn*32 + ni*16 + col] = acc[mi][ni][r];
    __syncthreads();
    const float am = *alpha_p;
    const int rr = tid >> 2, c16 = (tid & 3)*16;
    float* dst = &h[(size_t)(t0 + rr)*NH + n0 + c16];
    float ssum = 0.f;
    #pragma unroll
    for (int i = 0; i < 16; ++i) {
        float hn = dst[i] + am * Cs[rr*66 + c16 + i];
        dst[i] = hn;
        ssum += hn*hn;
    }
    ssum += __shfl_xor(ssum, 1, 64);
    ssum += __shfl_xor(ssum, 2, 64);
    if ((tid & 3) == 0) atomicAdd(&ss_out[t0 + rr], ssum);
}

// ---------------- head: logits = scale * head_w . a   (a pre-normed w/ head_rms)
template<bool PRE>
__global__ __launch_bounds__(256) void k_head(
    const bf16* __restrict__ a, const void* __restrict__ hw_p,
    const float* __restrict__ scale_p, float* __restrict__ out)
{
    __shared__ bf16 As[64*32], Bs[64*32];
    __shared__ float Ls[64*66];
    const int t0 = blockIdx.x*64, n0 = blockIdx.y*64;
    const int tid = threadIdx.x, lane = tid & 63, wv_ = tid >> 6;
    const int wm = wv_ >> 1, wn = wv_ & 1;
    const int srow = wv_*16 + (lane >> 2), sch = (lane & 3)*8;
    f32x4 acc[2][2] = {};
    for (int k0 = 0; k0 < NH; k0 += 32) {
        gload16(a + (size_t)(t0 + srow)*NH + k0 + sch, As + wv_*512);
        if constexpr (PRE) {
            gload16((const bf16*)hw_p + (size_t)(n0 + srow)*NH + k0 + sch, Bs + wv_*512);
        } else {
            const int r = tid >> 2, c8 = (tid & 3)*8;
            const float* src = (const float*)hw_p + (size_t)(n0 + r)*NH + k0 + c8;
            bf16x8 t;
            #pragma unroll
            for (int i = 0; i < 8; ++i) t[i] = f2bf(src[i]);
            *(bf16x8*)&Bs[r*32 + c8] = t;
        }
        __syncthreads();
        const int fr = lane & 15, kg = (lane >> 4)*8;
        bf16x8 a0 = *(const bf16x8*)&As[(wm*32 + fr)*32 + kg];
        bf16x8 a1 = *(const bf16x8*)&As[(wm*32 + 16 + fr)*32 + kg];
        bf16x8 b0 = *(const bf16x8*)&Bs[(wn*32 + fr)*32 + kg];
        bf16x8 b1 = *(const bf16x8*)&Bs[(wn*32 + 16 + fr)*32 + kg];
        acc[0][0] = __builtin_amdgcn_mfma_f32_16x16x32_bf16(a0, b0, acc[0][0], 0,0,0);
        acc[0][1] = __builtin_amdgcn_mfma_f32_16x16x32_bf16(a0, b1, acc[0][1], 0,0,0);
        acc[1][0] = __builtin_amdgcn_mfma_f32_16x16x32_bf16(a1, b0, acc[1][0], 0,0,0);
        acc[1][1] = __builtin_amdgcn_mfma_f32_16x16x32_bf16(a1, b1, acc[1][1], 0,0,0);
        __syncthreads();
    }
    const float sc = *scale_p;
    const int row4 = (lane >> 4)*4, col = lane & 15;
    #pragma unroll
    for (int mi = 0; mi < 2; ++mi)
      #pragma unroll
      for (int ni = 0; ni < 2; ++ni)
        #pragma unroll
        for (int r = 0; r < 4; ++r)
            Ls[(wm*32 + mi*16 + row4 + r)*66 + wn*32 + ni*16 + col] = sc * acc[mi][ni][r];
    __syncthreads();
    const int vv = tid >> 2, s16 = (tid & 3)*16;
    const int b = t0 >> 8, s0 = t0 & 255;
    float* dst = &out[((size_t)(b*NV + n0 + vv))*NS + s0 + s16];
    #pragma unroll
    for (int i = 0; i < 16; ++i) dst[i] = Ls[(s16 + i)*66 + vv];
}

extern "C" void kernel_launch(void* const* d_in, const int* in_sizes, int n_in,
                              void* d_out, int out_size, void* d_ws, size_t ws_size,
                              hipStream_t stream) {
    const float* x          = (const float*)d_in[0];
    const float* stem_w     = (const float*)d_in[1];
    const float* rms_local  = (const float*)d_in[2];
    const float* rms_global = (const float*)d_in[3];
    const float* rms_ffn    = (const float*)d_in[4];
    const float* alpha_local  = (const float*)d_in[5];
    const float* alpha_global = (const float*)d_in[6];
    const float* alpha_mlp    = (const float*)d_in[7];
    const float* w_local    = (const float*)d_in[8];
    const float* w_global   = (const float*)d_in[9];
    const float* wv         = (const float*)d_in[10];
    const float* wg         = (const float*)d_in[11];
    const float* wo         = (const float*)d_in[12];
    const float* head_rms   = (const float*)d_in[13];
    const float* head_scale = (const float*)d_in[14];
    const float* head_w     = (const float*)d_in[15];
    float* out = (float*)d_out;

    char* ws = (char*)d_ws;
    const size_t MB = 1024*1024;
    float* h    = (float*)(ws);                 // [0,4MB)
    bf16*  g    = (bf16*)(ws + 4*MB);           // [4,8MB)
    bf16*  a_bf = (bf16*)(ws + 8*MB);           // [8,10MB)
    float* ss   = (float*)(ws + 10*MB);         // 73*2048*4 = 584KB
    float* ss_rl = ss;
    float* ss_rg = ss + 24*NT;
    float* ss_rf = ss + 48*NT;
    float* ss_hd = ss + 72*NT;

    // bf16 weight cache region
    bf16* xT      = (bf16*)(ws + 16*MB);        // 2048*320*2 = 1.31MB
    bf16* stem_wb = (bf16*)(ws + 18*MB);        // 512*320*2
    bf16* head_wb = (bf16*)(ws + 19*MB);        // 256*512*2
    bf16* wv_b    = (bf16*)(ws + 20*MB);        // 24MB
    bf16* wg_b    = (bf16*)(ws + 44*MB);        // 24MB
    bf16* wo_b    = (bf16*)(ws + 68*MB);        // 24MB  -> end 92MB
    const bool pre = ws_size >= 92*MB;

    hipMemsetAsync(ss, 0, (size_t)73*NT*sizeof(float), stream);

    if (pre) {
        k_cvt<<<2048, 256, 0, stream>>>(wv, wv_b, NL*NG*NH/8);
        k_cvt<<<2048, 256, 0, stream>>>(wg, wg_b, NL*NG*NH/8);
        k_cvt<<<2048, 256, 0, stream>>>(wo, wo_b, NL*NH*NG/8);
        k_cvt<<<80, 256, 0, stream>>>(stem_w, stem_wb, NH*NC/8);
        k_cvt<<<64, 256, 0, stream>>>(head_w, head_wb, NV*NH/8);
        k_trx<<<dim3(4, 5, 8), 256, 0, stream>>>(x, xT);
        k_stem_b<<<dim3(32, 8), 256, 0, stream>>>(xT, stem_wb, h, ss_rl);
    } else {
        k_cvt<<<80, 256, 0, stream>>>(stem_w, stem_wb, NH*NC/8);   // fits in base? no — use direct
        // fallback: no cache region; stage stem through trx-less path using a_bf region is
        // not available either, so convert x via trx into g region (4MB >= 1.31MB)
        k_trx<<<dim3(4, 5, 8), 256, 0, stream>>>(x, (bf16*)g);
        // stem weights converted into a_bf region (2MB >= 0.33MB)
        k_cvt<<<80, 256, 0, stream>>>(stem_w, (bf16*)a_bf, NH*NC/8);
        k_stem_b<<<dim3(32, 8), 256, 0, stream>>>((bf16*)g, (bf16*)a_bf, h, ss_rl);
    }

    for (int l = 0; l < NL; ++l) {
        k_mix<1><<<dim3(128, 8), 256, 0, stream>>>(
            h, ss_rl + l*NT, w_local + (size_t)l*NH*256,
            rms_local + l*NH, alpha_local + l, ss_rg + l*NT);
        k_mix<16><<<dim3(128, 8), 256, 0, stream>>>(
            h, ss_rg + l*NT, w_global + (size_t)l*NH*256,
            rms_global + l*NH, alpha_global + l, ss_rf + l*NT);
        k_norm<<<512, 256, 0, stream>>>(h, ss_rf + l*NT, rms_ffn + l*NH, a_bf);
        float* ssn = (l == NL-1) ? ss_hd : (ss_rl + (l+1)*NT);
        if (pre) {
            k_mlp_in<true><<<dim3(32, 16), 256, 0, stream>>>(
                a_bf, wv_b + (size_t)l*NG*NH, wg_b + (size_t)l*NG*NH, g);
            k_mlp_out<true><<<dim3(32, 8), 256, 0, stream>>>(
                g, wo_b + (size_t)l*NH*NG, alpha_mlp + l, h, ssn);
        } else {
            k_mlp_in<false><<<dim3(32, 16), 256, 0, stream>>>(
                a_bf, wv + (size_t)l*NG*NH, wg + (size_t)l*NG*NH, g);
            k_mlp_out<false><<<dim3(32, 8), 256, 0, stream>>>(
                g, wo + (size_t)l*NH*NG, alpha_mlp + l, h, ssn);
        }
    }
    k_norm<<<512, 256, 0, stream>>>(h, ss_hd, head_rms, a_bf);
    if (pre) {
        k_head<true><<<dim3(32, 4), 256, 0, stream>>>(a_bf, head_wb, head_scale, out);
    } else {
        k_head<false><<<dim3(32, 4), 256, 0, stream>>>(a_bf, head_w, head_scale, out);
    }
}